// Round 12
// baseline (374.682 us; speedup 1.0000x reference)
//
#include <hip/hip_runtime.h>

typedef unsigned short u16;
typedef unsigned int   u32;
typedef __attribute__((ext_vector_type(8))) __bf16 bf16x8;
typedef __attribute__((ext_vector_type(4))) float  f32x4;
typedef __attribute__((ext_vector_type(4))) u32    u32x4;

#define AS1 __attribute__((address_space(1)))
#define AS3 __attribute__((address_space(3)))

// B=4096, K=64, D=128, H=2048, V=10000, IN=8640
// Permuted inp layout per row: [0,128) u | [128,8320) v | [8320,8576) extras | [8576,8640) pop

__device__ __forceinline__ u16 f2bf(float f) {
  u32 u = __builtin_bit_cast(u32, f);
  u += 0x7fffu + ((u >> 16) & 1u);   // RNE
  return (u16)(u >> 16);
}

__device__ __forceinline__ float wred(float v) {
#pragma unroll
  for (int off = 32; off > 0; off >>= 1) v += __shfl_xor(v, off, 64);
  return v;
}

__device__ __forceinline__ void stage16(const u16* g, u16* l) {
  __builtin_amdgcn_global_load_lds((const AS1 void*)g, (AS3 void*)l, 16, 0, 0);
}

// -------- W1 transpose helpers (R8-verified) --------
__device__ __forceinline__ int w1_orig_row(int p) {
  if (p < 128) return p;
  if (p < 8320) { int q = p - 128;  return 128 + (q >> 7) * 133 + (q & 127); }
  if (p < 8576) { int q = p - 8320; return 128 + (q >> 2) * 133 + 128 + (q & 3); }
  return 128 + (p - 8576) * 133 + 132;
}

__device__ __forceinline__ void w1_tile(const float* __restrict__ in,
                                        u16* __restrict__ out, int tile,
                                        u16 (*ls)[68], int t)
{
  const int p0 = (tile >> 5) << 6;
  const int h0 = (tile & 31) << 6;
  const int hl = t & 63, q = t >> 6;
#pragma unroll
  for (int i = 0; i < 16; i++) {
    int pl = i * 4 + q;
    int orig = w1_orig_row(p0 + pl);
    ls[hl][pl] = f2bf(in[(size_t)orig * 2048 + h0 + hl]);
  }
  __syncthreads();
  const int pp = t & 15, hq = t >> 4;
#pragma unroll
  for (int i = 0; i < 4; i++) {
    int hc = i * 16 + hq;
    uint2 vv = *(const uint2*)&ls[hc][pp * 4];
    *(uint2*)&out[(size_t)(h0 + hc) * 8640 + p0 + pp * 4] = vv;
  }
}

__device__ __forceinline__ void conv_tile(const float* __restrict__ in,
                                          u16* __restrict__ out, int R, int C,
                                          int tile, u16 (*ls)[68], int t)
{
  const int tiles_c = C >> 6;
  const int r0 = (tile / tiles_c) << 6;
  const int c0 = (tile % tiles_c) << 6;
  const int cl = t & 63, q = t >> 6;
#pragma unroll
  for (int i = 0; i < 16; i++) {
    int rl = i * 4 + q;
    ls[cl][rl] = f2bf(in[(size_t)(r0 + rl) * C + c0 + cl]);
  }
  __syncthreads();
  const int pp = t & 15, cq = t >> 4;
#pragma unroll
  for (int i = 0; i < 4; i++) {
    int cc = i * 16 + cq;
    uint2 vv = *(const uint2*)&ls[cc][pp * 4];
    *(uint2*)&out[(size_t)(c0 + cc) * R + r0 + pp * 4] = vv;
  }
}

// ======== prep: fused weight transposes (6400 blocks) + features (4096) ====
// Both memory-bound; fusing fills the machine for the whole ~260MB stream
// and removes 4 launch gaps + per-kernel ramp-down tails.
__global__ __launch_bounds__(256) void prep_kernel(
    const float* __restrict__ W1,  u16* __restrict__ w1t,
    const float* __restrict__ Wh1, u16* __restrict__ wh1t,
    const float* __restrict__ Wh2, u16* __restrict__ wh2t,
    const float* __restrict__ W2,  u16* __restrict__ w2t,
    const float* __restrict__ te, const int* __restrict__ nidx,
    const float* __restrict__ freq, const float* __restrict__ lut,
    u16* __restrict__ inp)
{
  __shared__ u16 ls[64][68];
  __shared__ float u_sh[128];
  __shared__ float squ_sh;
  const int bid = blockIdx.x, t = threadIdx.x;
  if (bid < 4320)      { w1_tile(W1, w1t, bid, ls, t); return; }
  if (bid < 5344)      { conv_tile(Wh1, wh1t, 2048, 2048, bid - 4320, ls, t); return; }
  if (bid < 6368)      { conv_tile(Wh2, wh2t, 2048, 2048, bid - 5344, ls, t); return; }
  if (bid < 6400)      { conv_tile(W2,  w2t,  2048, 64,   bid - 6368, ls, t); return; }

  // ---- feature body (R8-verified math: sqdist = squ+sqv-2dot, pol = dot) ----
  const int b = bid - 6400;
  const int l = t & 63, w = t >> 6;
  if (t < 128) u_sh[t] = te[(size_t)b * 128 + t];
  __syncthreads();
  if (w == 0) {
    float p = u_sh[l] * u_sh[l] + u_sh[l + 64] * u_sh[l + 64];
    p = wred(p);
    if (l == 0) squ_sh = p;
  }
  const size_t rb = (size_t)b * 8640;
  if (t < 64) {
    float2 u2 = *(const float2*)&u_sh[t * 2];
    u32 pk = (u32)f2bf(u2.x) | ((u32)f2bf(u2.y) << 16);
    *(u32*)&inp[rb + t * 2] = pk;
  }
  __syncthreads();

  const float squ = squ_sh;
  const float rsq = 1.0f - squ;
  const float2 u2 = *(const float2*)&u_sh[l * 2];

#pragma unroll
  for (int mk = 0; mk < 4; ++mk) {
    const int kbase = w * 16 + mk * 4;
    int idx[4]; float2 v2[4]; float sqv[4], dot[4];
#pragma unroll
    for (int j = 0; j < 4; j++) {
      idx[j] = nidx[b * 64 + kbase + j];
      v2[j] = *(const float2*)&lut[(size_t)idx[j] * 128 + l * 2];
    }
#pragma unroll
    for (int j = 0; j < 4; j++) {
      sqv[j] = v2[j].x * v2[j].x + v2[j].y * v2[j].y;
      dot[j] = u2.x * v2[j].x + u2.y * v2[j].y;
    }
#pragma unroll
    for (int off = 32; off > 0; off >>= 1) {
#pragma unroll
      for (int j = 0; j < 4; j++) {
        sqv[j] += __shfl_xor(sqv[j], off, 64);
        dot[j] += __shfl_xor(dot[j], off, 64);
      }
    }
#pragma unroll
    for (int j = 0; j < 4; j++) {
      u32 pk = (u32)f2bf(v2[j].x) | ((u32)f2bf(v2[j].y) << 16);
      *(u32*)&inp[rb + 128 + (size_t)(kbase + j) * 128 + l * 2] = pk;
    }
    float poin[4], cosv[4];
#pragma unroll
    for (int j = 0; j < 4; j++) {
      const float sqd = squ + sqv[j] - 2.0f * dot[j];
      float x = 1.0f + 2.0f * sqd / (rsq * (1.0f - sqv[j]));
      x = fmaxf(x, 1.0f + 1e-5f);
      poin[j] = logf(x + sqrtf(x * x - 1.0f));
      cosv[j] = dot[j] / fmaxf(sqrtf(squ * sqv[j]), 1e-8f);
    }
    if (l == 0) {
      u32x4 e0, e1;
#pragma unroll
      for (int j = 0; j < 2; j++) {
        e0[2 * j]     = (u32)f2bf(poin[j]) | ((u32)f2bf(cosv[j]) << 16);
        e0[2 * j + 1] = (u32)f2bf(dot[j])  | ((u32)f2bf(dot[j])  << 16);
        e1[2 * j]     = (u32)f2bf(poin[2 + j]) | ((u32)f2bf(cosv[2 + j]) << 16);
        e1[2 * j + 1] = (u32)f2bf(dot[2 + j])  | ((u32)f2bf(dot[2 + j])  << 16);
      }
      *(u32x4*)&inp[rb + 8320 + kbase * 4]     = e0;
      *(u32x4*)&inp[rb + 8320 + kbase * 4 + 8] = e1;
      u16 pp[4];
#pragma unroll
      for (int j = 0; j < 4; j++) pp[j] = f2bf(log1pf(freq[idx[j]]));
      *(u32*)&inp[rb + 8576 + kbase]     = (u32)pp[0] | ((u32)pp[1] << 16);
      *(u32*)&inp[rb + 8576 + kbase + 2] = (u32)pp[2] | ((u32)pp[3] << 16);
    }
  }
}

// ======== gemm2b: C(M,N) = relu(A(M,Kd)*BT(N,Kd)^T + bias), out bf16 ========
// BM=128 BN=128 BK=32. 4 waves (2Mx2N), wave tile 64x64 acc[4][4]. Ring-3 x
// 16KB = 48KB LDS -> 2 blocks/CU (grid 512): inter-block TLP overlaps LDS
// streams with MFMA (R11-confirmed, m114). Counted END-of-interval vmcnt(4)
// (T4): stage(ti+2) stays in flight across the barrier; only the last 2
// intervals drain to 0. Per interval: stage(ti+2) -> 8 swizzled ds_reads ->
// lgkm(0) -> 16 MFMA -> vmcnt(4) -> barrier. T2 swizzle is the BK=32
// restriction of the R6/R8 HW-verified mapping: phys_chunk = logical ^
// (row&3), pre-swizzled global source + linear gload_lds dest + swizzled
// ds_read (rule #21; 8 lanes per 4-bank group over the b128's 8 passes =
// balanced).
__global__ __launch_bounds__(256, 2) void gemm2b(
    const u16* __restrict__ A, const u16* __restrict__ BT,
    const float* __restrict__ bias, u16* __restrict__ out,
    int N, int Kd)
{
  extern __shared__ u16 lds[];   // 3 * 8192 u16 = 48KB
  const int t = threadIdx.x, l = t & 63, w = t >> 6;
  const int nb = N >> 7;
  const int cpx = gridDim.x >> 3;
  const int bid = (blockIdx.x & 7) * cpx + (blockIdx.x >> 3);
  const int bm = bid / nb, bn = bid % nb;
  const int m0 = bm << 7, n0 = bn << 7;
  const int vm = w >> 1, vn = w & 1;

  const size_t lda = (size_t)Kd;
  const int NT = Kd >> 5;

  // ---- staging constants (pre-swizzled global source) ----
  const int sr4 = l >> 2;                  // row within 16-row load
  const int q4  = (l & 3) ^ (sr4 & 3);     // logical chunk this lane fetches
  const u16* sA = A  + (size_t)(m0 + w * 32 + sr4) * lda + q4 * 8;
  const u16* sB = BT + (size_t)(n0 + w * 32 + sr4) * lda + q4 * 8;

  // ---- reader constants (swizzled ds_read) ----
  const int rl  = l & 15;
  const int swz = (((l >> 4)) ^ (rl & 3)) * 8;
  const int aOff = (vm * 64 + rl) * 32 + swz;          // + mi*512
  const int bOff = 4096 + (vn * 64 + rl) * 32 + swz;   // + ni*512

  f32x4 acc[4][4] = {};
  bf16x8 a[4], b[4];

  auto stageT = [&](int o, int tt) {
    const size_t kt = (size_t)tt * 32;
    stage16(sA + kt,            lds + o + (w * 2) * 512);
    stage16(sA + 16 * lda + kt, lds + o + (w * 2 + 1) * 512);
    stage16(sB + kt,            lds + o + 4096 + (w * 2) * 512);
    stage16(sB + 16 * lda + kt, lds + o + 4096 + (w * 2 + 1) * 512);
  };

  int o0 = 0, o1 = 8192, o2 = 16384;
  stageT(o0, 0);
  if (NT > 1) stageT(o1, 1);
  asm volatile("s_waitcnt vmcnt(4)" ::: "memory");   // stage(0) landed
  __builtin_amdgcn_s_barrier();

  for (int ti = 0; ti < NT; ++ti) {
    if (ti + 2 < NT) stageT(o2, ti + 2);   // overwrites buf(ti-1); its reads drained last interval
#pragma unroll
    for (int x = 0; x < 4; x++) b[x] = *(const bf16x8*)&lds[o0 + bOff + x * 512];
#pragma unroll
    for (int x = 0; x < 4; x++) a[x] = *(const bf16x8*)&lds[o0 + aOff + x * 512];
    asm volatile("s_waitcnt lgkmcnt(0)" ::: "memory");
    __builtin_amdgcn_sched_barrier(0);
    __builtin_amdgcn_s_setprio(1);
#pragma unroll
    for (int mi = 0; mi < 4; mi++)
#pragma unroll
      for (int ni = 0; ni < 4; ni++)
        acc[mi][ni] = __builtin_amdgcn_mfma_f32_16x16x32_bf16(a[mi], b[ni], acc[mi][ni], 0, 0, 0);
    __builtin_amdgcn_s_setprio(0);
    // retire stage(ti+1) before next interval reads it; keep stage(ti+2) flying
    if (ti + 2 < NT) asm volatile("s_waitcnt vmcnt(4)" ::: "memory");
    else             asm volatile("s_waitcnt vmcnt(0)" ::: "memory");
    __builtin_amdgcn_s_barrier();
    const int tmp = o0; o0 = o1; o1 = o2; o2 = tmp;
  }

  // ---- epilogue: direct bias+relu+store ----
  const int rq = l >> 4, rl2 = l & 15;
#pragma unroll
  for (int mi = 0; mi < 4; mi++) {
#pragma unroll
    for (int ni = 0; ni < 4; ni++) {
      const int col = n0 + vn * 64 + ni * 16 + rl2;
      const float bv = bias[col];
#pragma unroll
      for (int j = 0; j < 4; j++) {
        const int row = m0 + vm * 64 + mi * 16 + rq * 4 + j;
        float vv = acc[mi][ni][j] + bv;
        out[(size_t)row * N + col] = f2bf(fmaxf(vv, 0.0f));
      }
    }
  }
}

// -------- gemm4 split-K partial (R8) --------
__global__ __launch_bounds__(256, 2) void gemm4_part(
    const u16* __restrict__ A, const u16* __restrict__ BT,
    float* __restrict__ pbuf)
{
  __shared__ u16 lsA[2 * 128 * 32];
  __shared__ u16 lsB[2 * 64 * 32];
  const int t = threadIdx.x, l = t & 63, w = t >> 6;
  const int bmx = blockIdx.x & 31, sk = blockIdx.x >> 5;
  const int m0 = bmx << 7, k0 = sk << 9;
  float* pout = pbuf + (size_t)sk * 262144;
  const int wm = w >> 1, wn = w & 1;

  f32x4 acc[4][2] = {};
  const int srow = l >> 2, scol = (l & 3) * 8;

  const u16* pA0 = A  + (size_t)(m0 + w * 16 + srow)      * 2048 + scol + k0;
  const u16* pA1 = A  + (size_t)(m0 + 64 + w * 16 + srow) * 2048 + scol + k0;
  const u16* pB0 = BT + (size_t)(w * 16 + srow)           * 2048 + scol + k0;

  auto stage = [&](int buf, int kt) {
    u16* dA = lsA + buf * 4096;
    u16* dB = lsB + buf * 2048;
    stage16(pA0 + kt, dA + w * 512);
    stage16(pA1 + kt, dA + 2048 + w * 512);
    stage16(pB0 + kt, dB + w * 512);
  };

  stage(0, 0);
  __syncthreads();

  const int kk = (l >> 4) * 8;
  const int rl = l & 15;
  int cur = 0;
  for (int kt = 0; kt < 512; kt += 32) {
    if (kt + 32 < 512) stage(cur ^ 1, kt + 32);
    const u16* sA = lsA + cur * 4096;
    const u16* sB = lsB + cur * 2048;
    bf16x8 a[4], bb[2];
#pragma unroll
    for (int mi = 0; mi < 4; mi++)
      a[mi] = *(const bf16x8*)&sA[(wm * 64 + mi * 16 + rl) * 32 + kk];
#pragma unroll
    for (int ni = 0; ni < 2; ni++)
      bb[ni] = *(const bf16x8*)&sB[(wn * 32 + ni * 16 + rl) * 32 + kk];
#pragma unroll
    for (int mi = 0; mi < 4; mi++)
#pragma unroll
      for (int ni = 0; ni < 2; ni++)
        acc[mi][ni] = __builtin_amdgcn_mfma_f32_16x16x32_bf16(a[mi], bb[ni], acc[mi][ni], 0, 0, 0);
    __syncthreads();
    cur ^= 1;
  }

  const int rq = l >> 4, rl2 = l & 15;
#pragma unroll
  for (int mi = 0; mi < 4; mi++)
#pragma unroll
    for (int ni = 0; ni < 2; ni++) {
      const int col = wn * 32 + ni * 16 + rl2;
#pragma unroll
      for (int j = 0; j < 4; j++) {
        const int row = m0 + wm * 64 + mi * 16 + rq * 4 + j;
        pout[(size_t)row * 64 + col] = acc[mi][ni][j];
      }
    }
}

// -------- combine: sum 4 partials + bias -> sigmoid + BCE partials --------
__global__ __launch_bounds__(256) void gemm4_combine(
    const float* __restrict__ pbuf, const float* __restrict__ bias,
    const float* __restrict__ oneh, float* __restrict__ dist,
    float* __restrict__ part2)
{
  __shared__ float red[256];
  const int t = threadIdx.x;
  const size_t base = (size_t)blockIdx.x * 1024 + t * 4;
  f32x4 s = *(const f32x4*)&pbuf[base];
  s += *(const f32x4*)&pbuf[base + 262144];
  s += *(const f32x4*)&pbuf[base + 524288];
  s += *(const f32x4*)&pbuf[base + 786432];
  const int col0 = (int)(base & 63);
  f32x4 th = *(const f32x4*)&oneh[base];
  float lsum = 0.0f;
  f32x4 dv;
#pragma unroll
  for (int j = 0; j < 4; j++) {
    const float x = s[j] + bias[col0 + j];
    dv[j] = 1.0f / (1.0f + expf(-x));
    lsum += fmaxf(x, 0.0f) - x * th[j] + log1pf(expf(-fabsf(x)));
  }
  *(f32x4*)&dist[base] = dv;
  red[t] = lsum;
  __syncthreads();
  for (int s2 = 128; s2 > 0; s2 >>= 1) {
    if (t < s2) red[t] += red[t + s2];
    __syncthreads();
  }
  if (t == 0) part2[blockIdx.x] = red[0];
}

__global__ void loss_final(const float* __restrict__ part2, float* __restrict__ outloss) {
  const int l = threadIdx.x;
  float v = 0.0f;
#pragma unroll
  for (int i = 0; i < 4; i++) v += part2[l + i * 64];
  v = wred(v);
  if (l == 0) outloss[0] = v * (1.0f / 262144.0f);
}

// ---------------- launch ----------------
extern "C" void kernel_launch(void* const* d_in, const int* in_sizes, int n_in,
                              void* d_out, int out_size, void* d_ws, size_t ws_size,
                              hipStream_t stream)
{
  const float* te   = (const float*)d_in[0];
  const int*   nidx = (const int*)  d_in[1];
  const float* oneh = (const float*)d_in[2];
  const float* freq = (const float*)d_in[3];
  const float* lut  = (const float*)d_in[4];
  const float* W1   = (const float*)d_in[5];
  const float* b1   = (const float*)d_in[6];
  const float* Wh1  = (const float*)d_in[7];
  const float* bh1  = (const float*)d_in[8];
  const float* Wh2  = (const float*)d_in[9];
  const float* bh2  = (const float*)d_in[10];
  const float* W2   = (const float*)d_in[11];
  const float* b2   = (const float*)d_in[12];

  float* dist  = (float*)d_out;          // 4096*64
  float* lossp = dist + 262144;          // +1

  size_t off = 0;
  char* base = (char*)d_ws;
  auto alloc = [&](size_t bytes) { char* p = base + off; off += (bytes + 255) & ~(size_t)255; return p; };
  u16* inp   = (u16*)alloc((size_t)4096 * 8640 * 2);
  u16* w1t   = (u16*)alloc((size_t)2048 * 8640 * 2);
  u16* wh1t  = (u16*)alloc((size_t)2048 * 2048 * 2);
  u16* wh2t  = (u16*)alloc((size_t)2048 * 2048 * 2);
  u16* w2t   = (u16*)alloc((size_t)64 * 2048 * 2);
  u16* h1    = (u16*)alloc((size_t)4096 * 2048 * 2);
  float* part2 = (float*)alloc(1024);
  u16* h2 = inp;                  // inp dead after GEMM1
  u16* h3 = w1t;                  // w1t dead after GEMM1
  float* pbuf = (float*)wh1t;     // wh1t dead after GEMM2; 4MB < 8.4MB
  if (off > ws_size) return;

  (void)hipFuncSetAttribute((const void*)gemm2b,
                            hipFuncAttributeMaxDynamicSharedMemorySize, 49152);

  prep_kernel<<<10496, 256, 0, stream>>>(W1, w1t, Wh1, wh1t, Wh2, wh2t, W2, w2t,
                                         te, nidx, freq, lut, inp);

  gemm2b<<<512, 256, 49152, stream>>>(inp, w1t, b1, h1, 2048, 8640);
  gemm2b<<<512, 256, 49152, stream>>>(h1, wh1t, bh1, h2, 2048, 2048);
  gemm2b<<<512, 256, 49152, stream>>>(h2, wh2t, bh2, h3, 2048, 2048);
  gemm4_part   <<<128, 256, 0, stream>>>(h3, w2t, pbuf);
  gemm4_combine<<<256, 256, 0, stream>>>(pbuf, b2, oneh, dist, part2);
  loss_final   <<<1, 64, 0, stream>>>(part2, lossp);
}

// Round 13
// 316.733 us; speedup vs baseline: 1.1830x; 1.1830x over previous
//
#include <hip/hip_runtime.h>

typedef unsigned short u16;
typedef unsigned int   u32;
typedef __attribute__((ext_vector_type(8))) __bf16 bf16x8;
typedef __attribute__((ext_vector_type(4))) float  f32x4;
typedef __attribute__((ext_vector_type(4))) u32    u32x4;

#define AS1 __attribute__((address_space(1)))
#define AS3 __attribute__((address_space(3)))

// B=4096, K=64, D=128, H=2048, V=10000, IN=8640
// Permuted inp layout per row: [0,128) u | [128,8320) v | [8320,8576) extras | [8576,8640) pop

__device__ __forceinline__ u16 f2bf(float f) {
  u32 u = __builtin_bit_cast(u32, f);
  u += 0x7fffu + ((u >> 16) & 1u);   // RNE
  return (u16)(u >> 16);
}

__device__ __forceinline__ float wred(float v) {
#pragma unroll
  for (int off = 32; off > 0; off >>= 1) v += __shfl_xor(v, off, 64);
  return v;
}

__device__ __forceinline__ void stage16(const u16* g, u16* l) {
  __builtin_amdgcn_global_load_lds((const AS1 void*)g, (AS3 void*)l, 16, 0, 0);
}

// -------- W1 transpose helpers (R8-verified) --------
__device__ __forceinline__ int w1_orig_row(int p) {
  if (p < 128) return p;
  if (p < 8320) { int q = p - 128;  return 128 + (q >> 7) * 133 + (q & 127); }
  if (p < 8576) { int q = p - 8320; return 128 + (q >> 2) * 133 + 128 + (q & 3); }
  return 128 + (p - 8576) * 133 + 132;
}

__device__ __forceinline__ void w1_tile(const float* __restrict__ in,
                                        u16* __restrict__ out, int tile,
                                        u16 (*ls)[68], int t)
{
  const int p0 = (tile >> 5) << 6;
  const int h0 = (tile & 31) << 6;
  const int hl = t & 63, q = t >> 6;
#pragma unroll
  for (int i = 0; i < 16; i++) {
    int pl = i * 4 + q;
    int orig = w1_orig_row(p0 + pl);
    ls[hl][pl] = f2bf(in[(size_t)orig * 2048 + h0 + hl]);
  }
  __syncthreads();
  const int pp = t & 15, hq = t >> 4;
#pragma unroll
  for (int i = 0; i < 4; i++) {
    int hc = i * 16 + hq;
    uint2 vv = *(const uint2*)&ls[hc][pp * 4];
    *(uint2*)&out[(size_t)(h0 + hc) * 8640 + p0 + pp * 4] = vv;
  }
}

__device__ __forceinline__ void conv_tile(const float* __restrict__ in,
                                          u16* __restrict__ out, int R, int C,
                                          int tile, u16 (*ls)[68], int t)
{
  const int tiles_c = C >> 6;
  const int r0 = (tile / tiles_c) << 6;
  const int c0 = (tile % tiles_c) << 6;
  const int cl = t & 63, q = t >> 6;
#pragma unroll
  for (int i = 0; i < 16; i++) {
    int rl = i * 4 + q;
    ls[cl][rl] = f2bf(in[(size_t)(r0 + rl) * C + c0 + cl]);
  }
  __syncthreads();
  const int pp = t & 15, cq = t >> 4;
#pragma unroll
  for (int i = 0; i < 4; i++) {
    int cc = i * 16 + cq;
    uint2 vv = *(const uint2*)&ls[cc][pp * 4];
    *(uint2*)&out[(size_t)(c0 + cc) * R + r0 + pp * 4] = vv;
  }
}

// ======== prep: fused weight transposes (6400 blocks) + features (4096) ====
__global__ __launch_bounds__(256) void prep_kernel(
    const float* __restrict__ W1,  u16* __restrict__ w1t,
    const float* __restrict__ Wh1, u16* __restrict__ wh1t,
    const float* __restrict__ Wh2, u16* __restrict__ wh2t,
    const float* __restrict__ W2,  u16* __restrict__ w2t,
    const float* __restrict__ te, const int* __restrict__ nidx,
    const float* __restrict__ freq, const float* __restrict__ lut,
    u16* __restrict__ inp)
{
  __shared__ u16 ls[64][68];
  __shared__ float u_sh[128];
  __shared__ float squ_sh;
  const int bid = blockIdx.x, t = threadIdx.x;
  if (bid < 4320)      { w1_tile(W1, w1t, bid, ls, t); return; }
  if (bid < 5344)      { conv_tile(Wh1, wh1t, 2048, 2048, bid - 4320, ls, t); return; }
  if (bid < 6368)      { conv_tile(Wh2, wh2t, 2048, 2048, bid - 5344, ls, t); return; }
  if (bid < 6400)      { conv_tile(W2,  w2t,  2048, 64,   bid - 6368, ls, t); return; }

  // ---- feature body (R8-verified math: sqdist = squ+sqv-2dot, pol = dot) ----
  const int b = bid - 6400;
  const int l = t & 63, w = t >> 6;
  if (t < 128) u_sh[t] = te[(size_t)b * 128 + t];
  __syncthreads();
  if (w == 0) {
    float p = u_sh[l] * u_sh[l] + u_sh[l + 64] * u_sh[l + 64];
    p = wred(p);
    if (l == 0) squ_sh = p;
  }
  const size_t rb = (size_t)b * 8640;
  if (t < 64) {
    float2 u2 = *(const float2*)&u_sh[t * 2];
    u32 pk = (u32)f2bf(u2.x) | ((u32)f2bf(u2.y) << 16);
    *(u32*)&inp[rb + t * 2] = pk;
  }
  __syncthreads();

  const float squ = squ_sh;
  const float rsq = 1.0f - squ;
  const float2 u2 = *(const float2*)&u_sh[l * 2];

#pragma unroll
  for (int mk = 0; mk < 4; ++mk) {
    const int kbase = w * 16 + mk * 4;
    int idx[4]; float2 v2[4]; float sqv[4], dot[4];
#pragma unroll
    for (int j = 0; j < 4; j++) {
      idx[j] = nidx[b * 64 + kbase + j];
      v2[j] = *(const float2*)&lut[(size_t)idx[j] * 128 + l * 2];
    }
#pragma unroll
    for (int j = 0; j < 4; j++) {
      sqv[j] = v2[j].x * v2[j].x + v2[j].y * v2[j].y;
      dot[j] = u2.x * v2[j].x + u2.y * v2[j].y;
    }
#pragma unroll
    for (int off = 32; off > 0; off >>= 1) {
#pragma unroll
      for (int j = 0; j < 4; j++) {
        sqv[j] += __shfl_xor(sqv[j], off, 64);
        dot[j] += __shfl_xor(dot[j], off, 64);
      }
    }
#pragma unroll
    for (int j = 0; j < 4; j++) {
      u32 pk = (u32)f2bf(v2[j].x) | ((u32)f2bf(v2[j].y) << 16);
      *(u32*)&inp[rb + 128 + (size_t)(kbase + j) * 128 + l * 2] = pk;
    }
    float poin[4], cosv[4];
#pragma unroll
    for (int j = 0; j < 4; j++) {
      const float sqd = squ + sqv[j] - 2.0f * dot[j];
      float x = 1.0f + 2.0f * sqd / (rsq * (1.0f - sqv[j]));
      x = fmaxf(x, 1.0f + 1e-5f);
      poin[j] = logf(x + sqrtf(x * x - 1.0f));
      cosv[j] = dot[j] / fmaxf(sqrtf(squ * sqv[j]), 1e-8f);
    }
    if (l == 0) {
      u32x4 e0, e1;
#pragma unroll
      for (int j = 0; j < 2; j++) {
        e0[2 * j]     = (u32)f2bf(poin[j]) | ((u32)f2bf(cosv[j]) << 16);
        e0[2 * j + 1] = (u32)f2bf(dot[j])  | ((u32)f2bf(dot[j])  << 16);
        e1[2 * j]     = (u32)f2bf(poin[2 + j]) | ((u32)f2bf(cosv[2 + j]) << 16);
        e1[2 * j + 1] = (u32)f2bf(dot[2 + j])  | ((u32)f2bf(dot[2 + j])  << 16);
      }
      *(u32x4*)&inp[rb + 8320 + kbase * 4]     = e0;
      *(u32x4*)&inp[rb + 8320 + kbase * 4 + 8] = e1;
      u16 pp[4];
#pragma unroll
      for (int j = 0; j < 4; j++) pp[j] = f2bf(log1pf(freq[idx[j]]));
      *(u32*)&inp[rb + 8576 + kbase]     = (u32)pp[0] | ((u32)pp[1] << 16);
      *(u32*)&inp[rb + 8576 + kbase + 2] = (u32)pp[2] | ((u32)pp[3] << 16);
    }
  }
}

// ======== gemm2b (R11-verified): C = relu(A(M,Kd)*BT(N,Kd)^T + bias) ========
// BM=128 BN=128 BK=64. 4 waves (2Mx2N), wave tile 64x64 acc[4][4]. Ring-2 x
// 32KB = 64KB LDS -> 2 blocks/CU: inter-block TLP overlaps LDS streams with
// MFMA (m114; R11 measured 125us @ 54.8% MfmaUtil, 0 conflicts). Per
// interval: vmcnt(0) on interval-old stage -> barrier -> 16 swizzled
// ds_reads -> stage(ti+1) -> lgkm(8) -> 16 MFMA -> lgkm(0) -> 16 MFMA.
// (R13 tweak: reads issued before stage — reads gate MFMA, stage has a full
// interval of slack; buffer-overwrite safety is anchored at the barrier.)
// BK=64 is the MINIMUM conflict-free row width (R12 lesson: 64B rows are
// structurally 8-way conflicted). T2 slot-XOR swizzle both-sides.
__global__ __launch_bounds__(256, 2) void gemm2b(
    const u16* __restrict__ A, const u16* __restrict__ BT,
    const float* __restrict__ bias, u16* __restrict__ out,
    int N, int Kd)
{
  extern __shared__ u16 lds[];   // 2 * 16384 u16 = 64KB
  const int t = threadIdx.x, l = t & 63, w = t >> 6;
  const int nb = N >> 7;
  const int cpx = gridDim.x >> 3;
  const int bid = (blockIdx.x & 7) * cpx + (blockIdx.x >> 3);
  const int bm = bid / nb, bn = bid % nb;
  const int m0 = bm << 7, n0 = bn << 7;
  const int vm = w >> 1, vn = w & 1;

  const size_t lda = (size_t)Kd;
  const int NT = Kd >> 6;

  // ---- staging constants (pre-swizzled global source; R6-verified) ----
  const int sr = l >> 3;
  const int q  = (l & 7) ^ sr;
  const u16* sA = A  + (size_t)(m0 + w * 32 + sr) * lda + q * 8;
  const u16* sB = BT + (size_t)(n0 + w * 32 + sr) * lda + q * 8;
  const int dW = w * 2048;   // u16; per-buffer A at 0, B at 8192

  // ---- reader constants (swizzled ds_read; R6-verified formula) ----
  const int rl = l & 15;
  const int c0 = ((0 + (l >> 4)) ^ (rl & 7)) * 8;   // ks=0 chunk
  const int c1 = ((4 + (l >> 4)) ^ (rl & 7)) * 8;   // ks=1 chunk
  const int aBase = (vm * 64 + rl) * 64;            // + mi*1024
  const int bBase = 8192 + (vn * 64 + rl) * 64;     // + ni*1024

  f32x4 acc[4][4] = {};
  bf16x8 a0[4], a1[4], b0[4], b1[4];

  auto stageT = [&](int o, int tt) {
    const size_t kt = (size_t)tt * 64;
#pragma unroll
    for (int i = 0; i < 4; i++) {
      stage16(sA + (size_t)i * 8 * lda + kt, lds + o + dW + i * 512);
      stage16(sB + (size_t)i * 8 * lda + kt, lds + o + 8192 + dW + i * 512);
    }
  };
  auto mmq = [&](const bf16x8* a, const bf16x8* b) {
    __builtin_amdgcn_s_setprio(1);
#pragma unroll
    for (int mi = 0; mi < 4; mi++)
#pragma unroll
      for (int ni = 0; ni < 4; ni++)
        acc[mi][ni] = __builtin_amdgcn_mfma_f32_16x16x32_bf16(a[mi], b[ni], acc[mi][ni], 0, 0, 0);
    __builtin_amdgcn_s_setprio(0);
  };

  stageT(0, 0);   // prologue: tile 0 into buf0

  for (int ti = 0; ti < NT; ++ti) {
    const int o  = (ti & 1) ? 16384 : 0;
    const int on = o ^ 16384;
    // entry: my stage(ti) writes done (issued a full interval ago)
    asm volatile("s_waitcnt vmcnt(0)" ::: "memory");
    __builtin_amdgcn_s_barrier();   // all stage(ti) visible; all reads(ti-1) done
    // 16 ds_reads first (gate MFMA), then next-tile stage (has full-interval slack)
#pragma unroll
    for (int x = 0; x < 4; x++) b0[x] = *(const bf16x8*)&lds[o + bBase + x * 1024 + c0];
#pragma unroll
    for (int x = 0; x < 4; x++) a0[x] = *(const bf16x8*)&lds[o + aBase + x * 1024 + c0];
#pragma unroll
    for (int x = 0; x < 4; x++) b1[x] = *(const bf16x8*)&lds[o + bBase + x * 1024 + c1];
#pragma unroll
    for (int x = 0; x < 4; x++) a1[x] = *(const bf16x8*)&lds[o + aBase + x * 1024 + c1];
    if (ti + 1 < NT) stageT(on, ti + 1);   // overwrites buf(ti-1): reads drained pre-barrier
    asm volatile("s_waitcnt lgkmcnt(8)" ::: "memory");   // half0 frags landed
    __builtin_amdgcn_sched_barrier(0);
    mmq(a0, b0);                      // half1 reads drain underneath
    asm volatile("s_waitcnt lgkmcnt(0)" ::: "memory");
    __builtin_amdgcn_sched_barrier(0);
    mmq(a1, b1);
  }

  // ---- epilogue: direct bias+relu+store (disjoint 64x64 wave tiles) ----
  const int rq = l >> 4, rl2 = l & 15;
#pragma unroll
  for (int mi = 0; mi < 4; mi++) {
#pragma unroll
    for (int ni = 0; ni < 4; ni++) {
      const int col = n0 + vn * 64 + ni * 16 + rl2;
      const float bv = bias[col];
#pragma unroll
      for (int j = 0; j < 4; j++) {
        const int row = m0 + vm * 64 + mi * 16 + rq * 4 + j;
        float vv = acc[mi][ni][j] + bv;
        out[(size_t)row * N + col] = f2bf(fmaxf(vv, 0.0f));
      }
    }
  }
}

// -------- gemm4 split-K partial (R8) --------
__global__ __launch_bounds__(256, 2) void gemm4_part(
    const u16* __restrict__ A, const u16* __restrict__ BT,
    float* __restrict__ pbuf)
{
  __shared__ u16 lsA[2 * 128 * 32];
  __shared__ u16 lsB[2 * 64 * 32];
  const int t = threadIdx.x, l = t & 63, w = t >> 6;
  const int bmx = blockIdx.x & 31, sk = blockIdx.x >> 5;
  const int m0 = bmx << 7, k0 = sk << 9;
  float* pout = pbuf + (size_t)sk * 262144;
  const int wm = w >> 1, wn = w & 1;

  f32x4 acc[4][2] = {};
  const int srow = l >> 2, scol = (l & 3) * 8;

  const u16* pA0 = A  + (size_t)(m0 + w * 16 + srow)      * 2048 + scol + k0;
  const u16* pA1 = A  + (size_t)(m0 + 64 + w * 16 + srow) * 2048 + scol + k0;
  const u16* pB0 = BT + (size_t)(w * 16 + srow)           * 2048 + scol + k0;

  auto stage = [&](int buf, int kt) {
    u16* dA = lsA + buf * 4096;
    u16* dB = lsB + buf * 2048;
    stage16(pA0 + kt, dA + w * 512);
    stage16(pA1 + kt, dA + 2048 + w * 512);
    stage16(pB0 + kt, dB + w * 512);
  };

  stage(0, 0);
  __syncthreads();

  const int kk = (l >> 4) * 8;
  const int rl = l & 15;
  int cur = 0;
  for (int kt = 0; kt < 512; kt += 32) {
    if (kt + 32 < 512) stage(cur ^ 1, kt + 32);
    const u16* sA = lsA + cur * 4096;
    const u16* sB = lsB + cur * 2048;
    bf16x8 a[4], bb[2];
#pragma unroll
    for (int mi = 0; mi < 4; mi++)
      a[mi] = *(const bf16x8*)&sA[(wm * 64 + mi * 16 + rl) * 32 + kk];
#pragma unroll
    for (int ni = 0; ni < 2; ni++)
      bb[ni] = *(const bf16x8*)&sB[(wn * 32 + ni * 16 + rl) * 32 + kk];
#pragma unroll
    for (int mi = 0; mi < 4; mi++)
#pragma unroll
      for (int ni = 0; ni < 2; ni++)
        acc[mi][ni] = __builtin_amdgcn_mfma_f32_16x16x32_bf16(a[mi], bb[ni], acc[mi][ni], 0, 0, 0);
    __syncthreads();
    cur ^= 1;
  }

  const int rq = l >> 4, rl2 = l & 15;
#pragma unroll
  for (int mi = 0; mi < 4; mi++)
#pragma unroll
    for (int ni = 0; ni < 2; ni++) {
      const int col = wn * 32 + ni * 16 + rl2;
#pragma unroll
      for (int j = 0; j < 4; j++) {
        const int row = m0 + wm * 64 + mi * 16 + rq * 4 + j;
        pout[(size_t)row * 64 + col] = acc[mi][ni][j];
      }
    }
}

// -------- combine: sum 4 partials + bias -> sigmoid + BCE partials --------
__global__ __launch_bounds__(256) void gemm4_combine(
    const float* __restrict__ pbuf, const float* __restrict__ bias,
    const float* __restrict__ oneh, float* __restrict__ dist,
    float* __restrict__ part2)
{
  __shared__ float red[256];
  const int t = threadIdx.x;
  const size_t base = (size_t)blockIdx.x * 1024 + t * 4;
  f32x4 s = *(const f32x4*)&pbuf[base];
  s += *(const f32x4*)&pbuf[base + 262144];
  s += *(const f32x4*)&pbuf[base + 524288];
  s += *(const f32x4*)&pbuf[base + 786432];
  const int col0 = (int)(base & 63);
  f32x4 th = *(const f32x4*)&oneh[base];
  float lsum = 0.0f;
  f32x4 dv;
#pragma unroll
  for (int j = 0; j < 4; j++) {
    const float x = s[j] + bias[col0 + j];
    dv[j] = 1.0f / (1.0f + expf(-x));
    lsum += fmaxf(x, 0.0f) - x * th[j] + log1pf(expf(-fabsf(x)));
  }
  *(f32x4*)&dist[base] = dv;
  red[t] = lsum;
  __syncthreads();
  for (int s2 = 128; s2 > 0; s2 >>= 1) {
    if (t < s2) red[t] += red[t + s2];
    __syncthreads();
  }
  if (t == 0) part2[blockIdx.x] = red[0];
}

__global__ void loss_final(const float* __restrict__ part2, float* __restrict__ outloss) {
  const int l = threadIdx.x;
  float v = 0.0f;
#pragma unroll
  for (int i = 0; i < 4; i++) v += part2[l + i * 64];
  v = wred(v);
  if (l == 0) outloss[0] = v * (1.0f / 262144.0f);
}

// ---------------- launch ----------------
extern "C" void kernel_launch(void* const* d_in, const int* in_sizes, int n_in,
                              void* d_out, int out_size, void* d_ws, size_t ws_size,
                              hipStream_t stream)
{
  const float* te   = (const float*)d_in[0];
  const int*   nidx = (const int*)  d_in[1];
  const float* oneh = (const float*)d_in[2];
  const float* freq = (const float*)d_in[3];
  const float* lut  = (const float*)d_in[4];
  const float* W1   = (const float*)d_in[5];
  const float* b1   = (const float*)d_in[6];
  const float* Wh1  = (const float*)d_in[7];
  const float* bh1  = (const float*)d_in[8];
  const float* Wh2  = (const float*)d_in[9];
  const float* bh2  = (const float*)d_in[10];
  const float* W2   = (const float*)d_in[11];
  const float* b2   = (const float*)d_in[12];

  float* dist  = (float*)d_out;          // 4096*64
  float* lossp = dist + 262144;          // +1

  size_t off = 0;
  char* base = (char*)d_ws;
  auto alloc = [&](size_t bytes) { char* p = base + off; off += (bytes + 255) & ~(size_t)255; return p; };
  u16* inp   = (u16*)alloc((size_t)4096 * 8640 * 2);
  u16* w1t   = (u16*)alloc((size_t)2048 * 8640 * 2);
  u16* wh1t  = (u16*)alloc((size_t)2048 * 2048 * 2);
  u16* wh2t  = (u16*)alloc((size_t)2048 * 2048 * 2);
  u16* w2t   = (u16*)alloc((size_t)64 * 2048 * 2);
  u16* h1    = (u16*)alloc((size_t)4096 * 2048 * 2);
  float* part2 = (float*)alloc(1024);
  u16* h2 = inp;                  // inp dead after GEMM1
  u16* h3 = w1t;                  // w1t dead after GEMM1
  float* pbuf = (float*)wh1t;     // wh1t dead after GEMM2; 4MB < 8.4MB
  if (off > ws_size) return;

  (void)hipFuncSetAttribute((const void*)gemm2b,
                            hipFuncAttributeMaxDynamicSharedMemorySize, 65536);

  prep_kernel<<<10496, 256, 0, stream>>>(W1, w1t, Wh1, wh1t, Wh2, wh2t, W2, w2t,
                                         te, nidx, freq, lut, inp);

  gemm2b<<<512, 256, 65536, stream>>>(inp, w1t, b1, h1, 2048, 8640);
  gemm2b<<<512, 256, 65536, stream>>>(h1, wh1t, bh1, h2, 2048, 2048);
  gemm2b<<<512, 256, 65536, stream>>>(h2, wh2t, bh2, h3, 2048, 2048);
  gemm4_part   <<<128, 256, 0, stream>>>(h3, w2t, pbuf);
  gemm4_combine<<<256, 256, 0, stream>>>(pbuf, b2, oneh, dist, part2);
  loss_final   <<<1, 64, 0, stream>>>(part2, lossp);
}

// Round 14
// 268.146 us; speedup vs baseline: 1.3973x; 1.1812x over previous
//
#include <hip/hip_runtime.h>

typedef unsigned short u16;
typedef unsigned int   u32;
typedef __attribute__((ext_vector_type(8))) __bf16 bf16x8;
typedef __attribute__((ext_vector_type(4))) float  f32x4;
typedef __attribute__((ext_vector_type(4))) u32    u32x4;

#define AS1 __attribute__((address_space(1)))
#define AS3 __attribute__((address_space(3)))

// B=4096, K=64, D=128, H=2048, V=10000, IN=8640
// Permuted inp layout per row: [0,128) u | [128,8320) v | [8320,8576) extras | [8576,8640) pop

__device__ __forceinline__ u16 f2bf(float f) {
  return __builtin_bit_cast(u16, (__bf16)f);   // native v_cvt (RNE)
}
__device__ __forceinline__ u32 pk2(float x, float y) {
  // compiler fuses pair-casts into v_cvt_pk_bf16_f32 (m240: write casts, not asm)
  return (u32)__builtin_bit_cast(u16, (__bf16)x) |
         ((u32)__builtin_bit_cast(u16, (__bf16)y) << 16);
}

__device__ __forceinline__ float wred(float v) {
#pragma unroll
  for (int off = 32; off > 0; off >>= 1) v += __shfl_xor(v, off, 64);
  return v;
}

__device__ __forceinline__ void stage16(const u16* g, u16* l) {
  __builtin_amdgcn_global_load_lds((const AS1 void*)g, (AS3 void*)l, 16, 0, 0);
}

// -------- W1 transpose helpers (R14: 16-consecutive-p + packed b64 LDS writes) --------
__device__ __forceinline__ int w1_orig_row(int p) {
  if (p < 128) return p;
  if (p < 8320) { int q = p - 128;  return 128 + (q >> 7) * 133 + (q & 127); }
  if (p < 8576) { int q = p - 8320; return 128 + (q >> 2) * 133 + 128 + (q & 3); }
  return 128 + (p - 8576) * 133 + 132;
}

__device__ __forceinline__ void w1_tile(const float* __restrict__ in,
                                        u16* __restrict__ out, int tile,
                                        u16 (*ls)[68], int t)
{
  const int p0 = (tile >> 5) << 6;
  const int h0 = (tile & 31) << 6;
  const int hl = t & 63, q = t >> 6;
  float v[16];
#pragma unroll
  for (int i = 0; i < 16; i++) {
    int pl = q * 16 + i;
    int orig = w1_orig_row(p0 + pl);
    v[i] = in[(size_t)orig * 2048 + h0 + hl];   // coalesced: 64 lanes x consecutive h
  }
#pragma unroll
  for (int i = 0; i < 4; i++) {
    uint2 pk;
    pk.x = pk2(v[i * 4 + 0], v[i * 4 + 1]);
    pk.y = pk2(v[i * 4 + 2], v[i * 4 + 3]);
    *(uint2*)&ls[hl][q * 16 + i * 4] = pk;      // ds_write_b64, 2-way = free
  }
  __syncthreads();
  const int pp = t & 15, hq = t >> 4;
#pragma unroll
  for (int i = 0; i < 4; i++) {
    int hc = i * 16 + hq;
    uint2 vv = *(const uint2*)&ls[hc][pp * 4];
    *(uint2*)&out[(size_t)(h0 + hc) * 8640 + p0 + pp * 4] = vv;
  }
}

__device__ __forceinline__ void conv_tile(const float* __restrict__ in,
                                          u16* __restrict__ out, int R, int C,
                                          int tile, u16 (*ls)[68], int t)
{
  const int tiles_c = C >> 6;
  const int r0 = (tile / tiles_c) << 6;
  const int c0 = (tile % tiles_c) << 6;
  const int cl = t & 63, q = t >> 6;
  float v[16];
#pragma unroll
  for (int i = 0; i < 16; i++) {
    int rl = q * 16 + i;
    v[i] = in[(size_t)(r0 + rl) * C + c0 + cl];
  }
#pragma unroll
  for (int i = 0; i < 4; i++) {
    uint2 pk;
    pk.x = pk2(v[i * 4 + 0], v[i * 4 + 1]);
    pk.y = pk2(v[i * 4 + 2], v[i * 4 + 3]);
    *(uint2*)&ls[cl][q * 16 + i * 4] = pk;
  }
  __syncthreads();
  const int pp = t & 15, cq = t >> 4;
#pragma unroll
  for (int i = 0; i < 4; i++) {
    int cc = i * 16 + cq;
    uint2 vv = *(const uint2*)&ls[cc][pp * 4];
    *(uint2*)&out[(size_t)(c0 + cc) * R + r0 + pp * 4] = vv;
  }
}

// ======== prep: fused weight transposes (6400 blocks) + features (4096) ====
__global__ __launch_bounds__(256) void prep_kernel(
    const float* __restrict__ W1,  u16* __restrict__ w1t,
    const float* __restrict__ Wh1, u16* __restrict__ wh1t,
    const float* __restrict__ Wh2, u16* __restrict__ wh2t,
    const float* __restrict__ W2,  u16* __restrict__ w2t,
    const float* __restrict__ te, const int* __restrict__ nidx,
    const float* __restrict__ freq, const float* __restrict__ lut,
    u16* __restrict__ inp)
{
  __shared__ u16 ls[64][68];
  __shared__ float u_sh[128];
  __shared__ float squ_sh;
  const int bid = blockIdx.x, t = threadIdx.x;
  if (bid < 4320)      { w1_tile(W1, w1t, bid, ls, t); return; }
  if (bid < 5344)      { conv_tile(Wh1, wh1t, 2048, 2048, bid - 4320, ls, t); return; }
  if (bid < 6368)      { conv_tile(Wh2, wh2t, 2048, 2048, bid - 5344, ls, t); return; }
  if (bid < 6400)      { conv_tile(W2,  w2t,  2048, 64,   bid - 6368, ls, t); return; }

  // ---- feature body (sqdist = squ+sqv-2dot, pol = dot; lane-parallel extras) ----
  const int b = bid - 6400;
  const int l = t & 63, w = t >> 6;
  if (t < 128) u_sh[t] = te[(size_t)b * 128 + t];
  __syncthreads();
  if (w == 0) {
    float p = u_sh[l] * u_sh[l] + u_sh[l + 64] * u_sh[l + 64];
    p = wred(p);
    if (l == 0) squ_sh = p;
  }
  const size_t rb = (size_t)b * 8640;
  if (t < 64) {
    float2 u2 = *(const float2*)&u_sh[t * 2];
    *(u32*)&inp[rb + t * 2] = pk2(u2.x, u2.y);
  }
  __syncthreads();

  const float squ = squ_sh;
  const float rsq = 1.0f - squ;
  const float2 u2 = *(const float2*)&u_sh[l * 2];

#pragma unroll
  for (int mk = 0; mk < 4; ++mk) {
    const int kbase = w * 16 + mk * 4;
    int idx[4]; float2 v2[4]; float sqv[4], dot[4];
#pragma unroll
    for (int j = 0; j < 4; j++) {
      idx[j] = nidx[b * 64 + kbase + j];
      v2[j] = *(const float2*)&lut[(size_t)idx[j] * 128 + l * 2];
    }
#pragma unroll
    for (int j = 0; j < 4; j++) {
      sqv[j] = v2[j].x * v2[j].x + v2[j].y * v2[j].y;
      dot[j] = u2.x * v2[j].x + u2.y * v2[j].y;
    }
#pragma unroll
    for (int off = 32; off > 0; off >>= 1) {
#pragma unroll
      for (int j = 0; j < 4; j++) {
        sqv[j] += __shfl_xor(sqv[j], off, 64);
        dot[j] += __shfl_xor(dot[j], off, 64);
      }
    }
#pragma unroll
    for (int j = 0; j < 4; j++)
      *(u32*)&inp[rb + 128 + (size_t)(kbase + j) * 128 + l * 2] = pk2(v2[j].x, v2[j].y);

    // lane-class js = l&3 computes ONE extras set (selection via ?: — rule #20 safe)
    const int js = l & 3;
    const float sv = (js & 2) ? ((js & 1) ? sqv[3] : sqv[2]) : ((js & 1) ? sqv[1] : sqv[0]);
    const float dt = (js & 2) ? ((js & 1) ? dot[3] : dot[2]) : ((js & 1) ? dot[1] : dot[0]);
    const int   ix = (js & 2) ? ((js & 1) ? idx[3] : idx[2]) : ((js & 1) ? idx[1] : idx[0]);
    const float sqd = squ + sv - 2.0f * dt;
    float x = 1.0f + 2.0f * sqd / (rsq * (1.0f - sv));
    x = fmaxf(x, 1.0f + 1e-5f);
    const float poin = logf(x + sqrtf(x * x - 1.0f));
    const float cosv = dt / fmaxf(sqrtf(squ * sv), 1e-8f);
    if (l < 4) {
      *(u32*)&inp[rb + 8320 + (kbase + l) * 4]     = pk2(poin, cosv);
      *(u32*)&inp[rb + 8320 + (kbase + l) * 4 + 2] = pk2(dt, dt);
      inp[rb + 8576 + kbase + l] = f2bf(log1pf(freq[ix]));
    }
  }
}

// ======== gemm2b (R11/R13-verified): C = relu(A(M,Kd)*BT(N,Kd)^T + bias) ====
// BM=128 BN=128 BK=64. 4 waves (2Mx2N), wave tile 64x64 acc[4][4]. Ring-2 x
// 32KB = 64KB LDS -> 2 blocks/CU: inter-block TLP overlaps LDS streams with
// MFMA (m114). BK=64 = minimum conflict-free row width (R12). T2 slot-XOR
// swizzle both-sides. One barrier + vmcnt(0)-on-old-stage per interval.
__global__ __launch_bounds__(256, 2) void gemm2b(
    const u16* __restrict__ A, const u16* __restrict__ BT,
    const float* __restrict__ bias, u16* __restrict__ out,
    int N, int Kd)
{
  extern __shared__ u16 lds[];   // 2 * 16384 u16 = 64KB
  const int t = threadIdx.x, l = t & 63, w = t >> 6;
  const int nb = N >> 7;
  const int cpx = gridDim.x >> 3;
  const int bid = (blockIdx.x & 7) * cpx + (blockIdx.x >> 3);
  const int bm = bid / nb, bn = bid % nb;
  const int m0 = bm << 7, n0 = bn << 7;
  const int vm = w >> 1, vn = w & 1;

  const size_t lda = (size_t)Kd;
  const int NT = Kd >> 6;

  const int sr = l >> 3;
  const int q  = (l & 7) ^ sr;
  const u16* sA = A  + (size_t)(m0 + w * 32 + sr) * lda + q * 8;
  const u16* sB = BT + (size_t)(n0 + w * 32 + sr) * lda + q * 8;
  const int dW = w * 2048;

  const int rl = l & 15;
  const int c0 = ((0 + (l >> 4)) ^ (rl & 7)) * 8;
  const int c1 = ((4 + (l >> 4)) ^ (rl & 7)) * 8;
  const int aBase = (vm * 64 + rl) * 64;
  const int bBase = 8192 + (vn * 64 + rl) * 64;

  f32x4 acc[4][4] = {};
  bf16x8 a0[4], a1[4], b0[4], b1[4];

  auto stageT = [&](int o, int tt) {
    const size_t kt = (size_t)tt * 64;
#pragma unroll
    for (int i = 0; i < 4; i++) {
      stage16(sA + (size_t)i * 8 * lda + kt, lds + o + dW + i * 512);
      stage16(sB + (size_t)i * 8 * lda + kt, lds + o + 8192 + dW + i * 512);
    }
  };
  auto mmq = [&](const bf16x8* a, const bf16x8* b) {
    __builtin_amdgcn_s_setprio(1);
#pragma unroll
    for (int mi = 0; mi < 4; mi++)
#pragma unroll
      for (int ni = 0; ni < 4; ni++)
        acc[mi][ni] = __builtin_amdgcn_mfma_f32_16x16x32_bf16(a[mi], b[ni], acc[mi][ni], 0, 0, 0);
    __builtin_amdgcn_s_setprio(0);
  };

  stageT(0, 0);

  for (int ti = 0; ti < NT; ++ti) {
    const int o  = (ti & 1) ? 16384 : 0;
    const int on = o ^ 16384;
    asm volatile("s_waitcnt vmcnt(0)" ::: "memory");
    __builtin_amdgcn_s_barrier();
#pragma unroll
    for (int x = 0; x < 4; x++) b0[x] = *(const bf16x8*)&lds[o + bBase + x * 1024 + c0];
#pragma unroll
    for (int x = 0; x < 4; x++) a0[x] = *(const bf16x8*)&lds[o + aBase + x * 1024 + c0];
#pragma unroll
    for (int x = 0; x < 4; x++) b1[x] = *(const bf16x8*)&lds[o + bBase + x * 1024 + c1];
#pragma unroll
    for (int x = 0; x < 4; x++) a1[x] = *(const bf16x8*)&lds[o + aBase + x * 1024 + c1];
    if (ti + 1 < NT) stageT(on, ti + 1);
    asm volatile("s_waitcnt lgkmcnt(8)" ::: "memory");
    __builtin_amdgcn_sched_barrier(0);
    mmq(a0, b0);
    asm volatile("s_waitcnt lgkmcnt(0)" ::: "memory");
    __builtin_amdgcn_sched_barrier(0);
    mmq(a1, b1);
  }

  const int rq = l >> 4, rl2 = l & 15;
#pragma unroll
  for (int mi = 0; mi < 4; mi++) {
#pragma unroll
    for (int ni = 0; ni < 4; ni++) {
      const int col = n0 + vn * 64 + ni * 16 + rl2;
      const float bv = bias[col];
#pragma unroll
      for (int j = 0; j < 4; j++) {
        const int row = m0 + vm * 64 + mi * 16 + rq * 4 + j;
        float vv = acc[mi][ni][j] + bv;
        out[(size_t)row * N + col] = f2bf(fmaxf(vv, 0.0f));
      }
    }
  }
}

// -------- gemm4 split-K partial (R8) --------
__global__ __launch_bounds__(256, 2) void gemm4_part(
    const u16* __restrict__ A, const u16* __restrict__ BT,
    float* __restrict__ pbuf)
{
  __shared__ u16 lsA[2 * 128 * 32];
  __shared__ u16 lsB[2 * 64 * 32];
  const int t = threadIdx.x, l = t & 63, w = t >> 6;
  const int bmx = blockIdx.x & 31, sk = blockIdx.x >> 5;
  const int m0 = bmx << 7, k0 = sk << 9;
  float* pout = pbuf + (size_t)sk * 262144;
  const int wm = w >> 1, wn = w & 1;

  f32x4 acc[4][2] = {};
  const int srow = l >> 2, scol = (l & 3) * 8;

  const u16* pA0 = A  + (size_t)(m0 + w * 16 + srow)      * 2048 + scol + k0;
  const u16* pA1 = A  + (size_t)(m0 + 64 + w * 16 + srow) * 2048 + scol + k0;
  const u16* pB0 = BT + (size_t)(w * 16 + srow)           * 2048 + scol + k0;

  auto stage = [&](int buf, int kt) {
    u16* dA = lsA + buf * 4096;
    u16* dB = lsB + buf * 2048;
    stage16(pA0 + kt, dA + w * 512);
    stage16(pA1 + kt, dA + 2048 + w * 512);
    stage16(pB0 + kt, dB + w * 512);
  };

  stage(0, 0);
  __syncthreads();

  const int kk = (l >> 4) * 8;
  const int rl = l & 15;
  int cur = 0;
  for (int kt = 0; kt < 512; kt += 32) {
    if (kt + 32 < 512) stage(cur ^ 1, kt + 32);
    const u16* sA = lsA + cur * 4096;
    const u16* sB = lsB + cur * 2048;
    bf16x8 a[4], bb[2];
#pragma unroll
    for (int mi = 0; mi < 4; mi++)
      a[mi] = *(const bf16x8*)&sA[(wm * 64 + mi * 16 + rl) * 32 + kk];
#pragma unroll
    for (int ni = 0; ni < 2; ni++)
      bb[ni] = *(const bf16x8*)&sB[(wn * 32 + ni * 16 + rl) * 32 + kk];
#pragma unroll
    for (int mi = 0; mi < 4; mi++)
#pragma unroll
      for (int ni = 0; ni < 2; ni++)
        acc[mi][ni] = __builtin_amdgcn_mfma_f32_16x16x32_bf16(a[mi], bb[ni], acc[mi][ni], 0, 0, 0);
    __syncthreads();
    cur ^= 1;
  }

  const int rq = l >> 4, rl2 = l & 15;
#pragma unroll
  for (int mi = 0; mi < 4; mi++)
#pragma unroll
    for (int ni = 0; ni < 2; ni++) {
      const int col = wn * 32 + ni * 16 + rl2;
#pragma unroll
      for (int j = 0; j < 4; j++) {
        const int row = m0 + wm * 64 + mi * 16 + rq * 4 + j;
        pout[(size_t)row * 64 + col] = acc[mi][ni][j];
      }
    }
}

// -------- combine: sum 4 partials + bias -> sigmoid + BCE partials --------
__global__ __launch_bounds__(256) void gemm4_combine(
    const float* __restrict__ pbuf, const float* __restrict__ bias,
    const float* __restrict__ oneh, float* __restrict__ dist,
    float* __restrict__ part2)
{
  __shared__ float red[256];
  const int t = threadIdx.x;
  const size_t base = (size_t)blockIdx.x * 1024 + t * 4;
  f32x4 s = *(const f32x4*)&pbuf[base];
  s += *(const f32x4*)&pbuf[base + 262144];
  s += *(const f32x4*)&pbuf[base + 524288];
  s += *(const f32x4*)&pbuf[base + 786432];
  const int col0 = (int)(base & 63);
  f32x4 th = *(const f32x4*)&oneh[base];
  float lsum = 0.0f;
  f32x4 dv;
#pragma unroll
  for (int j = 0; j < 4; j++) {
    const float x = s[j] + bias[col0 + j];
    dv[j] = 1.0f / (1.0f + expf(-x));
    lsum += fmaxf(x, 0.0f) - x * th[j] + log1pf(expf(-fabsf(x)));
  }
  *(f32x4*)&dist[base] = dv;
  red[t] = lsum;
  __syncthreads();
  for (int s2 = 128; s2 > 0; s2 >>= 1) {
    if (t < s2) red[t] += red[t + s2];
    __syncthreads();
  }
  if (t == 0) part2[blockIdx.x] = red[0];
}

__global__ void loss_final(const float* __restrict__ part2, float* __restrict__ outloss) {
  const int l = threadIdx.x;
  float v = 0.0f;
#pragma unroll
  for (int i = 0; i < 4; i++) v += part2[l + i * 64];
  v = wred(v);
  if (l == 0) outloss[0] = v * (1.0f / 262144.0f);
}

// ---------------- launch ----------------
extern "C" void kernel_launch(void* const* d_in, const int* in_sizes, int n_in,
                              void* d_out, int out_size, void* d_ws, size_t ws_size,
                              hipStream_t stream)
{
  const float* te   = (const float*)d_in[0];
  const int*   nidx = (const int*)  d_in[1];
  const float* oneh = (const float*)d_in[2];
  const float* freq = (const float*)d_in[3];
  const float* lut  = (const float*)d_in[4];
  const float* W1   = (const float*)d_in[5];
  const float* b1   = (const float*)d_in[6];
  const float* Wh1  = (const float*)d_in[7];
  const float* bh1  = (const float*)d_in[8];
  const float* Wh2  = (const float*)d_in[9];
  const float* bh2  = (const float*)d_in[10];
  const float* W2   = (const float*)d_in[11];
  const float* b2   = (const float*)d_in[12];

  float* dist  = (float*)d_out;          // 4096*64
  float* lossp = dist + 262144;          // +1

  size_t off = 0;
  char* base = (char*)d_ws;
  auto alloc = [&](size_t bytes) { char* p = base + off; off += (bytes + 255) & ~(size_t)255; return p; };
  u16* inp   = (u16*)alloc((size_t)4096 * 8640 * 2);
  u16* w1t   = (u16*)alloc((size_t)2048 * 8640 * 2);
  u16* wh1t  = (u16*)alloc((size_t)2048 * 2048 * 2);
  u16* wh2t  = (u16*)alloc((size_t)2048 * 2048 * 2);
  u16* w2t   = (u16*)alloc((size_t)64 * 2048 * 2);
  u16* h1    = (u16*)alloc((size_t)4096 * 2048 * 2);
  float* part2 = (float*)alloc(1024);
  u16* h2 = inp;                  // inp dead after GEMM1
  u16* h3 = w1t;                  // w1t dead after GEMM1
  float* pbuf = (float*)wh1t;     // wh1t dead after GEMM2; 4MB < 8.4MB
  if (off > ws_size) return;

  (void)hipFuncSetAttribute((const void*)gemm2b,
                            hipFuncAttributeMaxDynamicSharedMemorySize, 65536);

  prep_kernel<<<10496, 256, 0, stream>>>(W1, w1t, Wh1, wh1t, Wh2, wh2t, W2, w2t,
                                         te, nidx, freq, lut, inp);

  gemm2b<<<512, 256, 65536, stream>>>(inp, w1t, b1, h1, 2048, 8640);
  gemm2b<<<512, 256, 65536, stream>>>(h1, wh1t, bh1, h2, 2048, 2048);
  gemm2b<<<512, 256, 65536, stream>>>(h2, wh2t, bh2, h3, 2048, 2048);
  gemm4_part   <<<128, 256, 0, stream>>>(h3, w2t, pbuf);
  gemm4_combine<<<256, 256, 0, stream>>>(pbuf, b2, oneh, dist, part2);
  loss_final   <<<1, 64, 0, stream>>>(part2, lossp);
}

// Round 15
// 266.231 us; speedup vs baseline: 1.4074x; 1.0072x over previous
//
#include <hip/hip_runtime.h>

typedef unsigned short u16;
typedef unsigned int   u32;
typedef __attribute__((ext_vector_type(8))) __bf16 bf16x8;
typedef __attribute__((ext_vector_type(4))) float  f32x4;
typedef __attribute__((ext_vector_type(4))) u32    u32x4;

#define AS1 __attribute__((address_space(1)))
#define AS3 __attribute__((address_space(3)))

// B=4096, K=64, D=128, H=2048, V=10000, IN=8640
// Permuted inp layout per row: [0,128) u | [128,8320) v | [8320,8576) extras | [8576,8640) pop

__device__ __forceinline__ u16 f2bf(float f) {
  return __builtin_bit_cast(u16, (__bf16)f);   // native v_cvt (RNE)
}
__device__ __forceinline__ u32 pk2(float x, float y) {
  return (u32)__builtin_bit_cast(u16, (__bf16)x) |
         ((u32)__builtin_bit_cast(u16, (__bf16)y) << 16);
}

__device__ __forceinline__ float wred(float v) {
#pragma unroll
  for (int off = 32; off > 0; off >>= 1) v += __shfl_xor(v, off, 64);
  return v;
}

__device__ __forceinline__ void stage16(const u16* g, u16* l) {
  __builtin_amdgcn_global_load_lds((const AS1 void*)g, (AS3 void*)l, 16, 0, 0);
}

// -------- W1 transpose helpers (R14-verified) --------
__device__ __forceinline__ int w1_orig_row(int p) {
  if (p < 128) return p;
  if (p < 8320) { int q = p - 128;  return 128 + (q >> 7) * 133 + (q & 127); }
  if (p < 8576) { int q = p - 8320; return 128 + (q >> 2) * 133 + 128 + (q & 3); }
  return 128 + (p - 8576) * 133 + 132;
}

__device__ __forceinline__ void w1_tile(const float* __restrict__ in,
                                        u16* __restrict__ out, int tile,
                                        u16 (*ls)[68], int t)
{
  const int p0 = (tile >> 5) << 6;
  const int h0 = (tile & 31) << 6;
  const int hl = t & 63, q = t >> 6;
  float v[16];
#pragma unroll
  for (int i = 0; i < 16; i++) {
    int pl = q * 16 + i;
    int orig = w1_orig_row(p0 + pl);
    v[i] = in[(size_t)orig * 2048 + h0 + hl];
  }
#pragma unroll
  for (int i = 0; i < 4; i++) {
    uint2 pk;
    pk.x = pk2(v[i * 4 + 0], v[i * 4 + 1]);
    pk.y = pk2(v[i * 4 + 2], v[i * 4 + 3]);
    *(uint2*)&ls[hl][q * 16 + i * 4] = pk;
  }
  __syncthreads();
  const int pp = t & 15, hq = t >> 4;
#pragma unroll
  for (int i = 0; i < 4; i++) {
    int hc = i * 16 + hq;
    uint2 vv = *(const uint2*)&ls[hc][pp * 4];
    *(uint2*)&out[(size_t)(h0 + hc) * 8640 + p0 + pp * 4] = vv;
  }
}

__device__ __forceinline__ void conv_tile(const float* __restrict__ in,
                                          u16* __restrict__ out, int R, int C,
                                          int tile, u16 (*ls)[68], int t)
{
  const int tiles_c = C >> 6;
  const int r0 = (tile / tiles_c) << 6;
  const int c0 = (tile % tiles_c) << 6;
  const int cl = t & 63, q = t >> 6;
  float v[16];
#pragma unroll
  for (int i = 0; i < 16; i++) {
    int rl = q * 16 + i;
    v[i] = in[(size_t)(r0 + rl) * C + c0 + cl];
  }
#pragma unroll
  for (int i = 0; i < 4; i++) {
    uint2 pk;
    pk.x = pk2(v[i * 4 + 0], v[i * 4 + 1]);
    pk.y = pk2(v[i * 4 + 2], v[i * 4 + 3]);
    *(uint2*)&ls[cl][q * 16 + i * 4] = pk;
  }
  __syncthreads();
  const int pp = t & 15, cq = t >> 4;
#pragma unroll
  for (int i = 0; i < 4; i++) {
    int cc = i * 16 + cq;
    uint2 vv = *(const uint2*)&ls[cc][pp * 4];
    *(uint2*)&out[(size_t)(c0 + cc) * R + r0 + pp * 4] = vv;
  }
}

// ======== prep: fused weight transposes (6400 blocks) + features (4096) ====
__global__ __launch_bounds__(256) void prep_kernel(
    const float* __restrict__ W1,  u16* __restrict__ w1t,
    const float* __restrict__ Wh1, u16* __restrict__ wh1t,
    const float* __restrict__ Wh2, u16* __restrict__ wh2t,
    const float* __restrict__ W2,  u16* __restrict__ w2t,
    const float* __restrict__ te, const int* __restrict__ nidx,
    const float* __restrict__ freq, const float* __restrict__ lut,
    u16* __restrict__ inp)
{
  __shared__ u16 ls[64][68];
  __shared__ float u_sh[128];
  __shared__ float squ_sh;
  const int bid = blockIdx.x, t = threadIdx.x;
  if (bid < 4320)      { w1_tile(W1, w1t, bid, ls, t); return; }
  if (bid < 5344)      { conv_tile(Wh1, wh1t, 2048, 2048, bid - 4320, ls, t); return; }
  if (bid < 6368)      { conv_tile(Wh2, wh2t, 2048, 2048, bid - 5344, ls, t); return; }
  if (bid < 6400)      { conv_tile(W2,  w2t,  2048, 64,   bid - 6368, ls, t); return; }

  // ---- feature body (sqdist = squ+sqv-2dot, pol = dot; lane-parallel extras) ----
  const int b = bid - 6400;
  const int l = t & 63, w = t >> 6;
  if (t < 128) u_sh[t] = te[(size_t)b * 128 + t];
  __syncthreads();
  if (w == 0) {
    float p = u_sh[l] * u_sh[l] + u_sh[l + 64] * u_sh[l + 64];
    p = wred(p);
    if (l == 0) squ_sh = p;
  }
  const size_t rb = (size_t)b * 8640;
  if (t < 64) {
    float2 u2 = *(const float2*)&u_sh[t * 2];
    *(u32*)&inp[rb + t * 2] = pk2(u2.x, u2.y);
  }
  __syncthreads();

  const float squ = squ_sh;
  const float rsq = 1.0f - squ;
  const float2 u2 = *(const float2*)&u_sh[l * 2];

#pragma unroll
  for (int mk = 0; mk < 4; ++mk) {
    const int kbase = w * 16 + mk * 4;
    int idx[4]; float2 v2[4]; float sqv[4], dot[4];
#pragma unroll
    for (int j = 0; j < 4; j++) {
      idx[j] = nidx[b * 64 + kbase + j];
      v2[j] = *(const float2*)&lut[(size_t)idx[j] * 128 + l * 2];
    }
#pragma unroll
    for (int j = 0; j < 4; j++) {
      sqv[j] = v2[j].x * v2[j].x + v2[j].y * v2[j].y;
      dot[j] = u2.x * v2[j].x + u2.y * v2[j].y;
    }
#pragma unroll
    for (int off = 32; off > 0; off >>= 1) {
#pragma unroll
      for (int j = 0; j < 4; j++) {
        sqv[j] += __shfl_xor(sqv[j], off, 64);
        dot[j] += __shfl_xor(dot[j], off, 64);
      }
    }
#pragma unroll
    for (int j = 0; j < 4; j++)
      *(u32*)&inp[rb + 128 + (size_t)(kbase + j) * 128 + l * 2] = pk2(v2[j].x, v2[j].y);

    const int js = l & 3;
    const float sv = (js & 2) ? ((js & 1) ? sqv[3] : sqv[2]) : ((js & 1) ? sqv[1] : sqv[0]);
    const float dt = (js & 2) ? ((js & 1) ? dot[3] : dot[2]) : ((js & 1) ? dot[1] : dot[0]);
    const int   ix = (js & 2) ? ((js & 1) ? idx[3] : idx[2]) : ((js & 1) ? idx[1] : idx[0]);
    const float sqd = squ + sv - 2.0f * dt;
    float x = 1.0f + 2.0f * sqd / (rsq * (1.0f - sv));
    x = fmaxf(x, 1.0f + 1e-5f);
    const float poin = logf(x + sqrtf(x * x - 1.0f));
    const float cosv = dt / fmaxf(sqrtf(squ * sv), 1e-8f);
    if (l < 4) {
      *(u32*)&inp[rb + 8320 + (kbase + l) * 4]     = pk2(poin, cosv);
      *(u32*)&inp[rb + 8320 + (kbase + l) * 4 + 2] = pk2(dt, dt);
      inp[rb + 8576 + kbase + l] = f2bf(log1pf(freq[ix]));
    }
  }
}

// ======== gemm2k: C = relu(A(M,Kd)*BT(N,Kd)^T + bias), out bf16 ========
// BM=128 BN=128 BK=64. 4 waves = 2 kg (K32 halves) x 2 vn; wave tile 128x64,
// acc[8][4]. Ring-2 x 32KB = 64KB LDS -> 2 blocks/CU (R11-confirmed m114
// inter-block overlap) PLUS R6's low-traffic geometry: 12 ds_read_b128 per
// thread-interval (192B) vs R11's 16 (256B) -> LDS/CU/interval 192->160KB.
// Stager byte-identical to R11 (0 conflicts); reader chunk formula
// (kg*4+(l>>4))^(rl&7) is R6's measured-0-conflict pattern; kg-combine
// epilogue is R3's coalesced l*4-f32 layout (NOT R10's conflicted l*16).
// One barrier + vmcnt(0)-on-old-stage per interval (R13 discipline).
__global__ __launch_bounds__(256, 2) void gemm2k(
    const u16* __restrict__ A, const u16* __restrict__ BT,
    const float* __restrict__ bias, u16* __restrict__ out,
    int N, int Kd)
{
  extern __shared__ u16 lds[];   // 2 * 16384 u16 = 64KB
  const int t = threadIdx.x, l = t & 63, w = t >> 6;
  const int nb = N >> 7;
  const int cpx = gridDim.x >> 3;
  const int bid = (blockIdx.x & 7) * cpx + (blockIdx.x >> 3);
  const int bm = bid / nb, bn = bid % nb;
  const int m0 = bm << 7, n0 = bn << 7;
  const int kg = w >> 1, vn = w & 1;

  const size_t lda = (size_t)Kd;
  const int NT = Kd >> 6;

  // ---- staging constants (pre-swizzled global source; R11 byte-identical) ----
  const int sr = l >> 3;
  const int q  = (l & 7) ^ sr;
  const u16* sA = A  + (size_t)(m0 + w * 32 + sr) * lda + q * 8;
  const u16* sB = BT + (size_t)(n0 + w * 32 + sr) * lda + q * 8;
  const int dW = w * 2048;   // per-buffer: A at [0,8192), B at [8192,16384) u16

  // ---- reader constants (swizzled ds_read; R6 kg formula) ----
  const int rl = l & 15;
  const int cK = ((kg * 4 + (l >> 4)) ^ (rl & 7)) * 8;   // this wave's K32 chunk
  const int aBase = rl * 64;                  // + mi*1024, mi=0..7 (all 128 rows)
  const int bBase = 8192 + (vn * 64 + rl) * 64;   // + ni*1024

  f32x4 acc[8][4] = {};
  bf16x8 a[8], b[4];

  auto stageT = [&](int o, int tt) {
    const size_t kt = (size_t)tt * 64;
#pragma unroll
    for (int i = 0; i < 4; i++) {
      stage16(sA + (size_t)i * 8 * lda + kt, lds + o + dW + i * 512);
      stage16(sB + (size_t)i * 8 * lda + kt, lds + o + 8192 + dW + i * 512);
    }
  };

  stageT(0, 0);   // prologue: tile 0 into buf0

  for (int ti = 0; ti < NT; ++ti) {
    const int o  = (ti & 1) ? 16384 : 0;
    const int on = o ^ 16384;
    asm volatile("s_waitcnt vmcnt(0)" ::: "memory");   // my stage(ti) done
    __builtin_amdgcn_s_barrier();   // all stage(ti) visible; all reads(ti-1) done
    // 12 ds_reads: B(4) then A(8); stage(ti+1) after (full-interval slack)
#pragma unroll
    for (int x = 0; x < 4; x++) b[x] = *(const bf16x8*)&lds[o + bBase + x * 1024 + cK];
#pragma unroll
    for (int x = 0; x < 8; x++) a[x] = *(const bf16x8*)&lds[o + aBase + x * 1024 + cK];
    if (ti + 1 < NT) stageT(on, ti + 1);
    asm volatile("s_waitcnt lgkmcnt(8)" ::: "memory");   // B + a0..a3 landed
    __builtin_amdgcn_sched_barrier(0);
    __builtin_amdgcn_s_setprio(1);
#pragma unroll
    for (int mi = 0; mi < 4; mi++)
#pragma unroll
      for (int ni = 0; ni < 4; ni++)
        acc[mi][ni] = __builtin_amdgcn_mfma_f32_16x16x32_bf16(a[mi], b[ni], acc[mi][ni], 0, 0, 0);
    __builtin_amdgcn_s_setprio(0);
    asm volatile("s_waitcnt lgkmcnt(0)" ::: "memory");   // a4..a7 landed
    __builtin_amdgcn_sched_barrier(0);
    __builtin_amdgcn_s_setprio(1);
#pragma unroll
    for (int mi = 4; mi < 8; mi++)
#pragma unroll
      for (int ni = 0; ni < 4; ni++)
        acc[mi][ni] = __builtin_amdgcn_mfma_f32_16x16x32_bf16(a[mi], b[ni], acc[mi][ni], 0, 0, 0);
    __builtin_amdgcn_s_setprio(0);
  }

  // ---- kg-combine via LDS (R3 layout: f32x4 at l*4 stride — coalesced) ----
  __syncthreads();
  float* pl = (float*)lds;
  if (kg == 1) {
#pragma unroll
    for (int mi = 0; mi < 8; mi++)
#pragma unroll
      for (int ni = 0; ni < 4; ni++)
        *(f32x4*)&pl[vn * 8192 + (mi * 4 + ni) * 256 + l * 4] = acc[mi][ni];
  }
  __syncthreads();
  if (kg == 0) {
    const int rq = l >> 4, rl2 = l & 15;
#pragma unroll
    for (int mi = 0; mi < 8; mi++) {
#pragma unroll
      for (int ni = 0; ni < 4; ni++) {
        f32x4 p2 = *(const f32x4*)&pl[vn * 8192 + (mi * 4 + ni) * 256 + l * 4];
        const int col = n0 + vn * 64 + ni * 16 + rl2;
        const float bv = bias[col];
#pragma unroll
        for (int j = 0; j < 4; j++) {
          const int row = m0 + mi * 16 + rq * 4 + j;
          float vv = acc[mi][ni][j] + p2[j] + bv;
          out[(size_t)row * N + col] = f2bf(fmaxf(vv, 0.0f));
        }
      }
    }
  }
}

// -------- gemm4 split-K partial (R8) --------
__global__ __launch_bounds__(256, 2) void gemm4_part(
    const u16* __restrict__ A, const u16* __restrict__ BT,
    float* __restrict__ pbuf)
{
  __shared__ u16 lsA[2 * 128 * 32];
  __shared__ u16 lsB[2 * 64 * 32];
  const int t = threadIdx.x, l = t & 63, w = t >> 6;
  const int bmx = blockIdx.x & 31, sk = blockIdx.x >> 5;
  const int m0 = bmx << 7, k0 = sk << 9;
  float* pout = pbuf + (size_t)sk * 262144;
  const int wm = w >> 1, wn = w & 1;

  f32x4 acc[4][2] = {};
  const int srow = l >> 2, scol = (l & 3) * 8;

  const u16* pA0 = A  + (size_t)(m0 + w * 16 + srow)      * 2048 + scol + k0;
  const u16* pA1 = A  + (size_t)(m0 + 64 + w * 16 + srow) * 2048 + scol + k0;
  const u16* pB0 = BT + (size_t)(w * 16 + srow)           * 2048 + scol + k0;

  auto stage = [&](int buf, int kt) {
    u16* dA = lsA + buf * 4096;
    u16* dB = lsB + buf * 2048;
    stage16(pA0 + kt, dA + w * 512);
    stage16(pA1 + kt, dA + 2048 + w * 512);
    stage16(pB0 + kt, dB + w * 512);
  };

  stage(0, 0);
  __syncthreads();

  const int kk = (l >> 4) * 8;
  const int rl = l & 15;
  int cur = 0;
  for (int kt = 0; kt < 512; kt += 32) {
    if (kt + 32 < 512) stage(cur ^ 1, kt + 32);
    const u16* sA = lsA + cur * 4096;
    const u16* sB = lsB + cur * 2048;
    bf16x8 a[4], bb[2];
#pragma unroll
    for (int mi = 0; mi < 4; mi++)
      a[mi] = *(const bf16x8*)&sA[(wm * 64 + mi * 16 + rl) * 32 + kk];
#pragma unroll
    for (int ni = 0; ni < 2; ni++)
      bb[ni] = *(const bf16x8*)&sB[(wn * 32 + ni * 16 + rl) * 32 + kk];
#pragma unroll
    for (int mi = 0; mi < 4; mi++)
#pragma unroll
      for (int ni = 0; ni < 2; ni++)
        acc[mi][ni] = __builtin_amdgcn_mfma_f32_16x16x32_bf16(a[mi], bb[ni], acc[mi][ni], 0, 0, 0);
    __syncthreads();
    cur ^= 1;
  }

  const int rq = l >> 4, rl2 = l & 15;
#pragma unroll
  for (int mi = 0; mi < 4; mi++)
#pragma unroll
    for (int ni = 0; ni < 2; ni++) {
      const int col = wn * 32 + ni * 16 + rl2;
#pragma unroll
      for (int j = 0; j < 4; j++) {
        const int row = m0 + wm * 64 + mi * 16 + rq * 4 + j;
        pout[(size_t)row * 64 + col] = acc[mi][ni][j];
      }
    }
}

// -------- combine: sum 4 partials + bias -> sigmoid + BCE partials --------
__global__ __launch_bounds__(256) void gemm4_combine(
    const float* __restrict__ pbuf, const float* __restrict__ bias,
    const float* __restrict__ oneh, float* __restrict__ dist,
    float* __restrict__ part2)
{
  __shared__ float red[256];
  const int t = threadIdx.x;
  const size_t base = (size_t)blockIdx.x * 1024 + t * 4;
  f32x4 s = *(const f32x4*)&pbuf[base];
  s += *(const f32x4*)&pbuf[base + 262144];
  s += *(const f32x4*)&pbuf[base + 524288];
  s += *(const f32x4*)&pbuf[base + 786432];
  const int col0 = (int)(base & 63);
  f32x4 th = *(const f32x4*)&oneh[base];
  float lsum = 0.0f;
  f32x4 dv;
#pragma unroll
  for (int j = 0; j < 4; j++) {
    const float x = s[j] + bias[col0 + j];
    dv[j] = 1.0f / (1.0f + expf(-x));
    lsum += fmaxf(x, 0.0f) - x * th[j] + log1pf(expf(-fabsf(x)));
  }
  *(f32x4*)&dist[base] = dv;
  red[t] = lsum;
  __syncthreads();
  for (int s2 = 128; s2 > 0; s2 >>= 1) {
    if (t < s2) red[t] += red[t + s2];
    __syncthreads();
  }
  if (t == 0) part2[blockIdx.x] = red[0];
}

__global__ void loss_final(const float* __restrict__ part2, float* __restrict__ outloss) {
  const int l = threadIdx.x;
  float v = 0.0f;
#pragma unroll
  for (int i = 0; i < 4; i++) v += part2[l + i * 64];
  v = wred(v);
  if (l == 0) outloss[0] = v * (1.0f / 262144.0f);
}

// ---------------- launch ----------------
extern "C" void kernel_launch(void* const* d_in, const int* in_sizes, int n_in,
                              void* d_out, int out_size, void* d_ws, size_t ws_size,
                              hipStream_t stream)
{
  const float* te   = (const float*)d_in[0];
  const int*   nidx = (const int*)  d_in[1];
  const float* oneh = (const float*)d_in[2];
  const float* freq = (const float*)d_in[3];
  const float* lut  = (const float*)d_in[4];
  const float* W1   = (const float*)d_in[5];
  const float* b1   = (const float*)d_in[6];
  const float* Wh1  = (const float*)d_in[7];
  const float* bh1  = (const float*)d_in[8];
  const float* Wh2  = (const float*)d_in[9];
  const float* bh2  = (const float*)d_in[10];
  const float* W2   = (const float*)d_in[11];
  const float* b2   = (const float*)d_in[12];

  float* dist  = (float*)d_out;          // 4096*64
  float* lossp = dist + 262144;          // +1

  size_t off = 0;
  char* base = (char*)d_ws;
  auto alloc = [&](size_t bytes) { char* p = base + off; off += (bytes + 255) & ~(size_t)255; return p; };
  u16* inp   = (u16*)alloc((size_t)4096 * 8640 * 2);
  u16* w1t   = (u16*)alloc((size_t)2048 * 8640 * 2);
  u16* wh1t  = (u16*)alloc((size_t)2048 * 2048 * 2);
  u16* wh2t  = (u16*)alloc((size_t)2048 * 2048 * 2);
  u16* w2t   = (u16*)alloc((size_t)64 * 2048 * 2);
  u16* h1    = (u16*)alloc((size_t)4096 * 2048 * 2);
  float* part2 = (float*)alloc(1024);
  u16* h2 = inp;                  // inp dead after GEMM1
  u16* h3 = w1t;                  // w1t dead after GEMM1
  float* pbuf = (float*)wh1t;     // wh1t dead after GEMM2; 4MB < 8.4MB
  if (off > ws_size) return;

  (void)hipFuncSetAttribute((const void*)gemm2k,
                            hipFuncAttributeMaxDynamicSharedMemorySize, 65536);

  prep_kernel<<<10496, 256, 0, stream>>>(W1, w1t, Wh1, wh1t, Wh2, wh2t, W2, w2t,
                                         te, nidx, freq, lut, inp);

  gemm2k<<<512, 256, 65536, stream>>>(inp, w1t, b1, h1, 2048, 8640);
  gemm2k<<<512, 256, 65536, stream>>>(h1, wh1t, bh1, h2, 2048, 2048);
  gemm2k<<<512, 256, 65536, stream>>>(h2, wh2t, bh2, h3, 2048, 2048);
  gemm4_part   <<<128, 256, 0, stream>>>(h3, w2t, pbuf);
  gemm4_combine<<<256, 256, 0, stream>>>(pbuf, b2, oneh, dist, part2);
  loss_final   <<<1, 64, 0, stream>>>(part2, lossp);
}